// Round 1
// baseline (302.480 us; speedup 1.0000x reference)
//
#include <hip/hip_runtime.h>

#define FEAT 128
#define HID  128

// ---------------------------------------------------------------------------
// Kernel 1: A = X @ W1[:F], B = X @ W1[F:]   (N x 128 each, fp32)
// Block: 256 threads -> 64 nodes x 64 cols tile, 4x4 micro-tile per thread.
// grid.y in {0,1} selects column half. Two passes per block: Wa then Wb.
// LDS: xs 64x129 (pad -> 2-way read conflicts, free), ws 128x64.
// ---------------------------------------------------------------------------
__global__ __launch_bounds__(256) void gemm_ab(
    const float* __restrict__ X, const float* __restrict__ W1,
    float* __restrict__ A, float* __restrict__ B, int N) {
  __shared__ float xs[64 * 129];
  __shared__ float ws[128 * 64];
  const int t = threadIdx.x;
  const int n0 = blockIdx.x * 64;
  const int j0 = blockIdx.y * 64;

  // stage X tile (64 nodes x 128 feats), LDS row stride 129
  {
    const int i0 = (t & 31) * 4;
    int nl = t >> 5;
    for (int rep = 0; rep < 8; ++rep, nl += 8) {
      const int n = n0 + nl;
      float4 v = make_float4(0.f, 0.f, 0.f, 0.f);
      if (n < N) v = *(const float4*)(X + (size_t)n * FEAT + i0);
      float* p = &xs[nl * 129 + i0];
      p[0] = v.x; p[1] = v.y; p[2] = v.z; p[3] = v.w;
    }
  }

  const int tn = t & 15;   // node group 0..15 -> nodes tn*4..tn*4+3
  const int tc = t >> 4;   // col group 0..15  -> cols  tc*4..tc*4+3

  for (int pass = 0; pass < 2; ++pass) {
    __syncthreads();  // xs ready / previous ws consumers done
    {
      const int cl4 = (t & 15) * 4;
      int i = t >> 4;
      for (int rep = 0; rep < 8; ++rep, i += 16) {
        *(float4*)&ws[i * 64 + cl4] =
            *(const float4*)(W1 + (size_t)(pass * FEAT + i) * HID + j0 + cl4);
      }
    }
    __syncthreads();

    float acc[4][4];
#pragma unroll
    for (int r = 0; r < 4; ++r)
#pragma unroll
      for (int c = 0; c < 4; ++c) acc[r][c] = 0.f;

#pragma unroll 4
    for (int i = 0; i < FEAT; ++i) {
      const float4 wv = *(const float4*)&ws[i * 64 + tc * 4];
      float xv[4];
#pragma unroll
      for (int r = 0; r < 4; ++r) xv[r] = xs[(tn * 4 + r) * 129 + i];
#pragma unroll
      for (int r = 0; r < 4; ++r) {
        acc[r][0] = fmaf(xv[r], wv.x, acc[r][0]);
        acc[r][1] = fmaf(xv[r], wv.y, acc[r][1]);
        acc[r][2] = fmaf(xv[r], wv.z, acc[r][2]);
        acc[r][3] = fmaf(xv[r], wv.w, acc[r][3]);
      }
    }

    float* O = pass ? B : A;
#pragma unroll
    for (int r = 0; r < 4; ++r) {
      const int n = n0 + tn * 4 + r;
      if (n < N) {
        float4 v = make_float4(acc[r][0], acc[r][1], acc[r][2], acc[r][3]);
        *(float4*)(O + (size_t)n * HID + j0 + tc * 4) = v;
      }
    }
  }
}

// ---------------------------------------------------------------------------
// Kernel 2: CSR row offsets from sorted src via binary search. rs has N+1 ents.
// ---------------------------------------------------------------------------
__global__ __launch_bounds__(256) void row_offsets(
    const int* __restrict__ src, int* __restrict__ rs, int N, int E) {
  const int n = blockIdx.x * 256 + threadIdx.x;
  if (n > N) return;
  int lo = 0, hi = E;
  while (lo < hi) {
    const int mid = (lo + hi) >> 1;
    if (src[mid] < n) lo = mid + 1; else hi = mid;
  }
  rs[n] = lo;
}

// ---------------------------------------------------------------------------
// Kernel 3: z[e] = W2 . relu(A[src[e]] + B[dst[e]] + b1) + b2
// Half-wave (32 lanes) per edge, float4 per lane, shfl tree reduce.
// ---------------------------------------------------------------------------
__global__ __launch_bounds__(256) void edge_z(
    const float* __restrict__ A, const float* __restrict__ B,
    const float* __restrict__ b1, const float* __restrict__ W2,
    const float* __restrict__ b2, const int* __restrict__ src,
    const int* __restrict__ dst, float* __restrict__ z, int E) {
  const int e = blockIdx.x * 8 + (threadIdx.x >> 5);
  if (e >= E) return;
  const int l = threadIdx.x & 31;
  const int u = src[e], v = dst[e];
  const float4 a  = *(const float4*)(A  + (size_t)u * HID + l * 4);
  const float4 b  = *(const float4*)(B  + (size_t)v * HID + l * 4);
  const float4 bb = *(const float4*)(b1 + l * 4);
  const float4 w  = *(const float4*)(W2 + l * 4);
  float p = fmaxf(a.x + b.x + bb.x, 0.f) * w.x
          + fmaxf(a.y + b.y + bb.y, 0.f) * w.y
          + fmaxf(a.z + b.z + bb.z, 0.f) * w.z
          + fmaxf(a.w + b.w + bb.w, 0.f) * w.w;
#pragma unroll
  for (int m = 16; m >= 1; m >>= 1) p += __shfl_xor(p, m);
  if (l == 0) z[e] = p + b2[0];
}

// ---------------------------------------------------------------------------
// Kernel 4: per-node log-softmax + K Gumbel-softmax rounds. Wave per node.
// Segment-constant terms (zmax, log denom, m2) cancel in both argmax and
// softmax, so reduction order only perturbs outputs at ~1 ulp.
// ---------------------------------------------------------------------------
__global__ __launch_bounds__(256) void seg_sample(
    const float* __restrict__ z, const float* __restrict__ U,
    const int* __restrict__ dst, const int* __restrict__ rs,
    float* __restrict__ out_sel, float* __restrict__ out_soft,
    int N, int E, int K) {
  const int n = blockIdx.x * 4 + (threadIdx.x >> 6);
  if (n >= N) return;
  const int lane = threadIdx.x & 63;
  const int start = rs[n];
  const int deg = rs[n + 1] - start;
  const float TAU = 0.9991f;

  if (deg == 0) {  // jax segment_max identity for int32 -> INT32_MIN
    if (lane == 0)
      for (int k = 0; k < K; ++k) out_sel[(size_t)k * N + n] = -2147483648.0f;
    return;
  }

  if (deg <= 64) {
    const bool act = lane < deg;
    const int e = start + (act ? lane : 0);
    const float zv = act ? z[e] : -INFINITY;
    const int d = act ? dst[e] : -1;
    float zmax = zv;
#pragma unroll
    for (int m = 32; m >= 1; m >>= 1) zmax = fmaxf(zmax, __shfl_xor(zmax, m));
    float den = act ? expf(zv - zmax) : 0.f;
#pragma unroll
    for (int m = 32; m >= 1; m >>= 1) den += __shfl_xor(den, m);
    const float lp = (zv - zmax) - logf(den);

    for (int k = 0; k < K; ++k) {
      float s = -INFINITY;
      if (act) {
        const float uu = U[(size_t)k * E + e];
        const float g = -logf(-logf(uu));
        s = (lp + g) / TAU;
      }
      float m2 = s;
#pragma unroll
      for (int m = 32; m >= 1; m >>= 1) m2 = fmaxf(m2, __shfl_xor(m2, m));
      float ex = act ? expf(s - m2) : 0.f;
      float d2 = ex;
#pragma unroll
      for (int m = 32; m >= 1; m >>= 1) d2 += __shfl_xor(d2, m);
      int cand = (act && s >= m2) ? d : -1;
#pragma unroll
      for (int m = 32; m >= 1; m >>= 1) cand = max(cand, __shfl_xor(cand, m));
      if (lane == 0) out_sel[(size_t)k * N + n] = (float)cand;
      if (act) out_soft[(size_t)k * E + e] = ex / d2;
    }
  } else {
    // generic fallback (deg > 64): chunked, recompute s per pass
    float zmax = -INFINITY;
    for (int c = lane; c < deg; c += 64) zmax = fmaxf(zmax, z[start + c]);
#pragma unroll
    for (int m = 32; m >= 1; m >>= 1) zmax = fmaxf(zmax, __shfl_xor(zmax, m));
    float den = 0.f;
    for (int c = lane; c < deg; c += 64) den += expf(z[start + c] - zmax);
#pragma unroll
    for (int m = 32; m >= 1; m >>= 1) den += __shfl_xor(den, m);
    const float logd = logf(den);

    for (int k = 0; k < K; ++k) {
      float m2 = -INFINITY;
      for (int c = lane; c < deg; c += 64) {
        const int e = start + c;
        const float g = -logf(-logf(U[(size_t)k * E + e]));
        const float s = ((z[e] - zmax) - logd + g) / TAU;
        m2 = fmaxf(m2, s);
      }
#pragma unroll
      for (int m = 32; m >= 1; m >>= 1) m2 = fmaxf(m2, __shfl_xor(m2, m));
      float d2 = 0.f;
      int cand = -1;
      for (int c = lane; c < deg; c += 64) {
        const int e = start + c;
        const float g = -logf(-logf(U[(size_t)k * E + e]));
        const float s = ((z[e] - zmax) - logd + g) / TAU;
        d2 += expf(s - m2);
        if (s >= m2) cand = max(cand, dst[e]);
      }
#pragma unroll
      for (int m = 32; m >= 1; m >>= 1) d2 += __shfl_xor(d2, m);
#pragma unroll
      for (int m = 32; m >= 1; m >>= 1) cand = max(cand, __shfl_xor(cand, m));
      if (lane == 0) out_sel[(size_t)k * N + n] = (float)cand;
      for (int c = lane; c < deg; c += 64) {
        const int e = start + c;
        const float g = -logf(-logf(U[(size_t)k * E + e]));
        const float s = ((z[e] - zmax) - logd + g) / TAU;
        out_soft[(size_t)k * E + e] = expf(s - m2) / d2;
      }
    }
  }
}

// ---------------------------------------------------------------------------
extern "C" void kernel_launch(void* const* d_in, const int* in_sizes, int n_in,
                              void* d_out, int out_size, void* d_ws, size_t ws_size,
                              hipStream_t stream) {
  const float* X  = (const float*)d_in[0];  // (N, 128)
  const float* W1 = (const float*)d_in[1];  // (256, 128)
  const float* b1 = (const float*)d_in[2];  // (128,)
  const float* W2 = (const float*)d_in[3];  // (128,)
  const float* b2 = (const float*)d_in[4];  // (1,)
  const float* U  = (const float*)d_in[5];  // (K, E)
  const int* src  = (const int*)d_in[6];    // (E,) sorted
  const int* dst  = (const int*)d_in[7];    // (E,)
  const int E = in_sizes[6];
  const int K = in_sizes[5] / E;
  const int N = in_sizes[0] / FEAT;

  // workspace: A (N*128 f32) | B (N*128 f32) | z (E f32) | rs (N+1 i32)
  float* A = (float*)d_ws;
  float* B = A + (size_t)N * HID;
  float* z = B + (size_t)N * HID;
  int* rs  = (int*)(z + E);

  float* out_sel  = (float*)d_out;                    // (K, N) as f32
  float* out_soft = (float*)d_out + (size_t)K * N;    // (K, E)

  dim3 gg((N + 63) / 64, 2);
  hipLaunchKernelGGL(gemm_ab, gg, dim3(256), 0, stream, X, W1, A, B, N);
  hipLaunchKernelGGL(row_offsets, dim3((N + 256) / 256), dim3(256), 0, stream,
                     src, rs, N, E);
  hipLaunchKernelGGL(edge_z, dim3((E + 7) / 8), dim3(256), 0, stream,
                     A, B, b1, W2, b2, src, dst, z, E);
  hipLaunchKernelGGL(seg_sample, dim3((N + 3) / 4), dim3(256), 0, stream,
                     z, U, dst, rs, out_sel, out_soft, N, E, K);
}

// Round 2
// 265.464 us; speedup vs baseline: 1.1394x; 1.1394x over previous
//
#include <hip/hip_runtime.h>

#define FEAT 128
#define HID  128
#define XS_STRIDE 68  // multiple of 4 (16B-aligned b128 reads), 68%32=4 -> 2-way bank alias (free)

// ---------------------------------------------------------------------------
// Kernel 1: A = X @ W1[:F], B = X @ W1[F:]   (N x 128 each, fp32)
// Block: 256 threads -> 64 nodes x 128 cols tile. Micro-tile 4 nodes x 8 cols.
// X tile staged TRANSPOSED in LDS (xs[k][node]) so the node-direction read is
// one ds_read_b128. W staged in 32-row k-chunks (16 KB). All LDS reads b128;
// W reads are 16-lane broadcasts (4 distinct addrs/wave) -> near-free.
// LDS total: 128*68*4 + 32*128*4 = 34.8 + 16 = 50.8 KB -> 3 blocks/CU.
// ---------------------------------------------------------------------------
__global__ __launch_bounds__(256) void gemm_ab(
    const float* __restrict__ X, const float* __restrict__ W1,
    float* __restrict__ A, float* __restrict__ B, int N) {
  __shared__ float xs[FEAT * XS_STRIDE];
  __shared__ float ws[32 * HID];
  const int t = threadIdx.x;
  const int n0 = blockIdx.x * 64;

  // stage X tile transposed: thread (nl = t>>2, fi = t&3) loads float4 at
  // feat f0 = fi*4 + rep*16; writes column-wise into xs[f][nl].
  {
    const int nl = t >> 2;
    const int fi = t & 3;
    const int n = n0 + nl;
    const bool ok = n < N;
    const float* xrow = X + (size_t)n * FEAT;
#pragma unroll
    for (int rep = 0; rep < 8; ++rep) {
      const int f0 = fi * 4 + rep * 16;
      float4 v = make_float4(0.f, 0.f, 0.f, 0.f);
      if (ok) v = *(const float4*)(xrow + f0);
      xs[(f0 + 0) * XS_STRIDE + nl] = v.x;
      xs[(f0 + 1) * XS_STRIDE + nl] = v.y;
      xs[(f0 + 2) * XS_STRIDE + nl] = v.z;
      xs[(f0 + 3) * XS_STRIDE + nl] = v.w;
    }
  }

  const int tn = t & 15;   // node group: nodes tn*4 .. tn*4+3
  const int tc = t >> 4;   // col group:  cols  tc*8 .. tc*8+7

  for (int pass = 0; pass < 2; ++pass) {
    float acc[4][8];
#pragma unroll
    for (int r = 0; r < 4; ++r)
#pragma unroll
      for (int c = 0; c < 8; ++c) acc[r][c] = 0.f;

    for (int kc = 0; kc < 4; ++kc) {
      __syncthreads();  // previous ws consumers done (and xs ready on 1st)
#pragma unroll
      for (int rep = 0; rep < 4; ++rep) {
        const int idx = rep * 256 + t;
        const int r = idx >> 5;
        const int c4 = (idx & 31) << 2;
        *(float4*)&ws[r * HID + c4] =
            *(const float4*)(W1 + (size_t)(pass * FEAT + kc * 32 + r) * HID + c4);
      }
      __syncthreads();

#pragma unroll 4
      for (int k = 0; k < 32; ++k) {
        const float4 xv = *(const float4*)&xs[(kc * 32 + k) * XS_STRIDE + tn * 4];
        const float4 w0 = *(const float4*)&ws[k * HID + tc * 8];
        const float4 w1 = *(const float4*)&ws[k * HID + tc * 8 + 4];
        const float xr[4] = {xv.x, xv.y, xv.z, xv.w};
#pragma unroll
        for (int r = 0; r < 4; ++r) {
          acc[r][0] = fmaf(xr[r], w0.x, acc[r][0]);
          acc[r][1] = fmaf(xr[r], w0.y, acc[r][1]);
          acc[r][2] = fmaf(xr[r], w0.z, acc[r][2]);
          acc[r][3] = fmaf(xr[r], w0.w, acc[r][3]);
          acc[r][4] = fmaf(xr[r], w1.x, acc[r][4]);
          acc[r][5] = fmaf(xr[r], w1.y, acc[r][5]);
          acc[r][6] = fmaf(xr[r], w1.z, acc[r][6]);
          acc[r][7] = fmaf(xr[r], w1.w, acc[r][7]);
        }
      }
    }

    float* O = pass ? B : A;
#pragma unroll
    for (int r = 0; r < 4; ++r) {
      const int n = n0 + tn * 4 + r;
      if (n < N) {
        *(float4*)(O + (size_t)n * HID + tc * 8) =
            make_float4(acc[r][0], acc[r][1], acc[r][2], acc[r][3]);
        *(float4*)(O + (size_t)n * HID + tc * 8 + 4) =
            make_float4(acc[r][4], acc[r][5], acc[r][6], acc[r][7]);
      }
    }
  }
}

// ---------------------------------------------------------------------------
// Kernel 2: CSR row offsets from sorted src via binary search. rs has N+1 ents.
// ---------------------------------------------------------------------------
__global__ __launch_bounds__(256) void row_offsets(
    const int* __restrict__ src, int* __restrict__ rs, int N, int E) {
  const int n = blockIdx.x * 256 + threadIdx.x;
  if (n > N) return;
  int lo = 0, hi = E;
  while (lo < hi) {
    const int mid = (lo + hi) >> 1;
    if (src[mid] < n) lo = mid + 1; else hi = mid;
  }
  rs[n] = lo;
}

// ---------------------------------------------------------------------------
// Kernel 3: z[e] = W2 . relu(A[src[e]] + B[dst[e]] + b1) + b2
// 16 lanes per edge (8 floats/lane), 2 edges per 16-lane group with all 8 row
// loads issued before any reduce -> 4x memory-level parallelism vs round-1.
// 4-step shfl_xor reduce. 32 edges per 256-thread block.
// ---------------------------------------------------------------------------
__global__ __launch_bounds__(256) void edge_z(
    const float* __restrict__ A, const float* __restrict__ B,
    const float* __restrict__ b1, const float* __restrict__ W2,
    const float* __restrict__ b2, const int* __restrict__ src,
    const int* __restrict__ dst, float* __restrict__ z, int E) {
  const int g = threadIdx.x >> 4;
  const int l = threadIdx.x & 15;
  const int e0 = blockIdx.x * 32 + g * 2;
  if (e0 >= E) return;
  const int e1 = e0 + 1;
  const bool has1 = e1 < E;

  const int u0 = src[e0], v0 = dst[e0];
  const int u1 = has1 ? src[e1] : u0;
  const int v1 = has1 ? dst[e1] : v0;

  const float4* Au0 = (const float4*)(A + (size_t)u0 * HID) + l * 2;
  const float4* Bv0 = (const float4*)(B + (size_t)v0 * HID) + l * 2;
  const float4* Au1 = (const float4*)(A + (size_t)u1 * HID) + l * 2;
  const float4* Bv1 = (const float4*)(B + (size_t)v1 * HID) + l * 2;

  // issue all 8 row loads up front
  const float4 a00 = Au0[0], a01 = Au0[1];
  const float4 b00 = Bv0[0], b01 = Bv0[1];
  const float4 a10 = Au1[0], a11 = Au1[1];
  const float4 b10 = Bv1[0], b11 = Bv1[1];

  const float4 c0 = *(const float4*)(b1 + l * 8);
  const float4 c1 = *(const float4*)(b1 + l * 8 + 4);
  const float4 w0 = *(const float4*)(W2 + l * 8);
  const float4 w1 = *(const float4*)(W2 + l * 8 + 4);
  const float bias2 = b2[0];

  float p0 = fmaxf(a00.x + b00.x + c0.x, 0.f) * w0.x
           + fmaxf(a00.y + b00.y + c0.y, 0.f) * w0.y
           + fmaxf(a00.z + b00.z + c0.z, 0.f) * w0.z
           + fmaxf(a00.w + b00.w + c0.w, 0.f) * w0.w
           + fmaxf(a01.x + b01.x + c1.x, 0.f) * w1.x
           + fmaxf(a01.y + b01.y + c1.y, 0.f) * w1.y
           + fmaxf(a01.z + b01.z + c1.z, 0.f) * w1.z
           + fmaxf(a01.w + b01.w + c1.w, 0.f) * w1.w;
  float p1 = fmaxf(a10.x + b10.x + c0.x, 0.f) * w0.x
           + fmaxf(a10.y + b10.y + c0.y, 0.f) * w0.y
           + fmaxf(a10.z + b10.z + c0.z, 0.f) * w0.z
           + fmaxf(a10.w + b10.w + c0.w, 0.f) * w0.w
           + fmaxf(a11.x + b11.x + c1.x, 0.f) * w1.x
           + fmaxf(a11.y + b11.y + c1.y, 0.f) * w1.y
           + fmaxf(a11.z + b11.z + c1.z, 0.f) * w1.z
           + fmaxf(a11.w + b11.w + c1.w, 0.f) * w1.w;

#pragma unroll
  for (int m = 8; m >= 1; m >>= 1) {
    p0 += __shfl_xor(p0, m);
    p1 += __shfl_xor(p1, m);
  }
  if (l == 0) {
    z[e0] = p0 + bias2;
    if (has1) z[e1] = p1 + bias2;
  }
}

// ---------------------------------------------------------------------------
// Kernel 4: per-node log-softmax + K Gumbel-softmax rounds. Wave per node.
// Segment-constant terms (zmax, log denom, m2) cancel in both argmax and
// softmax, so reduction order only perturbs outputs at ~1 ulp.
// ---------------------------------------------------------------------------
__global__ __launch_bounds__(256) void seg_sample(
    const float* __restrict__ z, const float* __restrict__ U,
    const int* __restrict__ dst, const int* __restrict__ rs,
    float* __restrict__ out_sel, float* __restrict__ out_soft,
    int N, int E, int K) {
  const int n = blockIdx.x * 4 + (threadIdx.x >> 6);
  if (n >= N) return;
  const int lane = threadIdx.x & 63;
  const int start = rs[n];
  const int deg = rs[n + 1] - start;
  const float TAU = 0.9991f;

  if (deg == 0) {  // jax segment_max identity for int32 -> INT32_MIN
    if (lane == 0)
      for (int k = 0; k < K; ++k) out_sel[(size_t)k * N + n] = -2147483648.0f;
    return;
  }

  if (deg <= 64) {
    const bool act = lane < deg;
    const int e = start + (act ? lane : 0);
    const float zv = act ? z[e] : -INFINITY;
    const int d = act ? dst[e] : -1;
    float zmax = zv;
#pragma unroll
    for (int m = 32; m >= 1; m >>= 1) zmax = fmaxf(zmax, __shfl_xor(zmax, m));
    float den = act ? expf(zv - zmax) : 0.f;
#pragma unroll
    for (int m = 32; m >= 1; m >>= 1) den += __shfl_xor(den, m);
    const float lp = (zv - zmax) - logf(den);

    for (int k = 0; k < K; ++k) {
      float s = -INFINITY;
      if (act) {
        const float uu = U[(size_t)k * E + e];
        const float g = -logf(-logf(uu));
        s = (lp + g) / TAU;
      }
      float m2 = s;
#pragma unroll
      for (int m = 32; m >= 1; m >>= 1) m2 = fmaxf(m2, __shfl_xor(m2, m));
      float ex = act ? expf(s - m2) : 0.f;
      float d2 = ex;
#pragma unroll
      for (int m = 32; m >= 1; m >>= 1) d2 += __shfl_xor(d2, m);
      int cand = (act && s >= m2) ? d : -1;
#pragma unroll
      for (int m = 32; m >= 1; m >>= 1) cand = max(cand, __shfl_xor(cand, m));
      if (lane == 0) out_sel[(size_t)k * N + n] = (float)cand;
      if (act) out_soft[(size_t)k * E + e] = ex / d2;
    }
  } else {
    // generic fallback (deg > 64): chunked, recompute s per pass
    float zmax = -INFINITY;
    for (int c = lane; c < deg; c += 64) zmax = fmaxf(zmax, z[start + c]);
#pragma unroll
    for (int m = 32; m >= 1; m >>= 1) zmax = fmaxf(zmax, __shfl_xor(zmax, m));
    float den = 0.f;
    for (int c = lane; c < deg; c += 64) den += expf(z[start + c] - zmax);
#pragma unroll
    for (int m = 32; m >= 1; m >>= 1) den += __shfl_xor(den, m);
    const float logd = logf(den);

    for (int k = 0; k < K; ++k) {
      float m2 = -INFINITY;
      for (int c = lane; c < deg; c += 64) {
        const int e = start + c;
        const float g = -logf(-logf(U[(size_t)k * E + e]));
        const float s = ((z[e] - zmax) - logd + g) / TAU;
        m2 = fmaxf(m2, s);
      }
#pragma unroll
      for (int m = 32; m >= 1; m >>= 1) m2 = fmaxf(m2, __shfl_xor(m2, m));
      float d2 = 0.f;
      int cand = -1;
      for (int c = lane; c < deg; c += 64) {
        const int e = start + c;
        const float g = -logf(-logf(U[(size_t)k * E + e]));
        const float s = ((z[e] - zmax) - logd + g) / TAU;
        d2 += expf(s - m2);
        if (s >= m2) cand = max(cand, dst[e]);
      }
#pragma unroll
      for (int m = 32; m >= 1; m >>= 1) d2 += __shfl_xor(d2, m);
#pragma unroll
      for (int m = 32; m >= 1; m >>= 1) cand = max(cand, __shfl_xor(cand, m));
      if (lane == 0) out_sel[(size_t)k * N + n] = (float)cand;
      for (int c = lane; c < deg; c += 64) {
        const int e = start + c;
        const float g = -logf(-logf(U[(size_t)k * E + e]));
        const float s = ((z[e] - zmax) - logd + g) / TAU;
        out_soft[(size_t)k * E + e] = expf(s - m2) / d2;
      }
    }
  }
}

// ---------------------------------------------------------------------------
extern "C" void kernel_launch(void* const* d_in, const int* in_sizes, int n_in,
                              void* d_out, int out_size, void* d_ws, size_t ws_size,
                              hipStream_t stream) {
  const float* X  = (const float*)d_in[0];  // (N, 128)
  const float* W1 = (const float*)d_in[1];  // (256, 128)
  const float* b1 = (const float*)d_in[2];  // (128,)
  const float* W2 = (const float*)d_in[3];  // (128,)
  const float* b2 = (const float*)d_in[4];  // (1,)
  const float* U  = (const float*)d_in[5];  // (K, E)
  const int* src  = (const int*)d_in[6];    // (E,) sorted
  const int* dst  = (const int*)d_in[7];    // (E,)
  const int E = in_sizes[6];
  const int K = in_sizes[5] / E;
  const int N = in_sizes[0] / FEAT;

  // workspace: A (N*128 f32) | B (N*128 f32) | z (E f32) | rs (N+1 i32)
  float* A = (float*)d_ws;
  float* B = A + (size_t)N * HID;
  float* z = B + (size_t)N * HID;
  int* rs  = (int*)(z + E);

  float* out_sel  = (float*)d_out;                    // (K, N) as f32
  float* out_soft = (float*)d_out + (size_t)K * N;    // (K, E)

  hipLaunchKernelGGL(gemm_ab, dim3((N + 63) / 64), dim3(256), 0, stream,
                     X, W1, A, B, N);
  hipLaunchKernelGGL(row_offsets, dim3((N + 256) / 256), dim3(256), 0, stream,
                     src, rs, N, E);
  hipLaunchKernelGGL(edge_z, dim3((E + 31) / 32), dim3(256), 0, stream,
                     A, B, b1, W2, b2, src, dst, z, E);
  hipLaunchKernelGGL(seg_sample, dim3((N + 3) / 4), dim3(256), 0, stream,
                     z, U, dst, rs, out_sel, out_soft, N, E, K);
}

// Round 3
// 237.445 us; speedup vs baseline: 1.2739x; 1.1180x over previous
//
#include <hip/hip_runtime.h>

#define FEAT 128
#define HID  128
#define XS_S 132  // 128 nodes + 4 pad; multiple of 4 keeps b128 alignment

// ---------------------------------------------------------------------------
// Kernel 1: [A|B] = X @ [W1[:128] | W1[128:]]  (N x 256 concat, fp32)
// Block: 256 threads -> 128 nodes x 64 concat-cols. Micro-tile 4 nodes x 8
// cols. K chunked by 32: xs = X^T chunk (32k x 128n, 16.9 KB), ws = W chunk
// (32k x 64c, 8 KB) -> 25 KB LDS -> 6 blocks/CU. Grid 391x4 = 1564 blocks.
// All inner LDS reads are b128; ws reads are 32-lane broadcasts.
// ---------------------------------------------------------------------------
__global__ __launch_bounds__(256) void gemm_ab(
    const float* __restrict__ X, const float* __restrict__ W1,
    float* __restrict__ A, float* __restrict__ B, int N) {
  __shared__ float xs[32 * XS_S];
  __shared__ float ws[32 * 64];
  const int t = threadIdx.x;
  const int n0 = blockIdx.x * 128;
  const int j0 = blockIdx.y * 64;  // concat col base: 0,64 -> A ; 128,192 -> B
  const float* Wbase = W1 + (j0 < 128 ? j0 : 128 * HID + (j0 - 128));
  float* Obase = (j0 < 128) ? (A + j0) : (B + (j0 - 128));

  const int tn = t & 31;  // node group: nodes tn*4 .. tn*4+3
  const int tc = t >> 5;  // col group:  cols  tc*8 .. tc*8+7

  float acc[4][8];
#pragma unroll
  for (int r = 0; r < 4; ++r)
#pragma unroll
    for (int c = 0; c < 8; ++c) acc[r][c] = 0.f;

  const int ln = t >> 3;       // staging node 0..31 (+rep*32)
  const int lf = (t & 7) * 4;  // staging k-local float4 base

  for (int kc = 0; kc < 4; ++kc) {
    __syncthreads();
    // stage X chunk transposed: xs[k_local][node]
#pragma unroll
    for (int rep = 0; rep < 4; ++rep) {
      const int nl = ln + rep * 32;
      const int n = n0 + nl;
      float4 v = make_float4(0.f, 0.f, 0.f, 0.f);
      if (n < N) v = *(const float4*)(X + (size_t)n * FEAT + kc * 32 + lf);
      xs[(lf + 0) * XS_S + nl] = v.x;
      xs[(lf + 1) * XS_S + nl] = v.y;
      xs[(lf + 2) * XS_S + nl] = v.z;
      xs[(lf + 3) * XS_S + nl] = v.w;
    }
    // stage W chunk: ws[k_local][col]
#pragma unroll
    for (int rep = 0; rep < 2; ++rep) {
      const int idx = rep * 256 + t;   // 0..511 float4s
      const int r = idx >> 4;          // 0..31
      const int c4 = (idx & 15) * 4;   // 0..60
      *(float4*)&ws[r * 64 + c4] =
          *(const float4*)(Wbase + (size_t)(kc * 32 + r) * HID + c4);
    }
    __syncthreads();

#pragma unroll 8
    for (int k = 0; k < 32; ++k) {
      const float4 xv = *(const float4*)&xs[k * XS_S + tn * 4];
      const float4 w0 = *(const float4*)&ws[k * 64 + tc * 8];
      const float4 w1 = *(const float4*)&ws[k * 64 + tc * 8 + 4];
      const float xr[4] = {xv.x, xv.y, xv.z, xv.w};
#pragma unroll
      for (int r = 0; r < 4; ++r) {
        acc[r][0] = fmaf(xr[r], w0.x, acc[r][0]);
        acc[r][1] = fmaf(xr[r], w0.y, acc[r][1]);
        acc[r][2] = fmaf(xr[r], w0.z, acc[r][2]);
        acc[r][3] = fmaf(xr[r], w0.w, acc[r][3]);
        acc[r][4] = fmaf(xr[r], w1.x, acc[r][4]);
        acc[r][5] = fmaf(xr[r], w1.y, acc[r][5]);
        acc[r][6] = fmaf(xr[r], w1.z, acc[r][6]);
        acc[r][7] = fmaf(xr[r], w1.w, acc[r][7]);
      }
    }
  }

#pragma unroll
  for (int r = 0; r < 4; ++r) {
    const int n = n0 + tn * 4 + r;
    if (n < N) {
      float* o = Obase + (size_t)n * HID + tc * 8;
      *(float4*)o = make_float4(acc[r][0], acc[r][1], acc[r][2], acc[r][3]);
      *(float4*)(o + 4) = make_float4(acc[r][4], acc[r][5], acc[r][6], acc[r][7]);
    }
  }
}

// ---------------------------------------------------------------------------
// Kernel 2: CSR row offsets from sorted src via binary search. rs has N+1 ents.
// ---------------------------------------------------------------------------
__global__ __launch_bounds__(256) void row_offsets(
    const int* __restrict__ src, int* __restrict__ rs, int N, int E) {
  const int n = blockIdx.x * 256 + threadIdx.x;
  if (n > N) return;
  int lo = 0, hi = E;
  while (lo < hi) {
    const int mid = (lo + hi) >> 1;
    if (src[mid] < n) lo = mid + 1; else hi = mid;
  }
  rs[n] = lo;
}

// ---------------------------------------------------------------------------
// Kernel 3: z[e] = W2 . relu(A[src[e]] + B[dst[e]] + b1) + b2
// 16 lanes per edge (8 floats/lane), 2 edges per 16-lane group, all 8 row
// loads issued before any reduce. 4-step shfl_xor reduce.
// ---------------------------------------------------------------------------
__global__ __launch_bounds__(256) void edge_z(
    const float* __restrict__ A, const float* __restrict__ B,
    const float* __restrict__ b1, const float* __restrict__ W2,
    const float* __restrict__ b2, const int* __restrict__ src,
    const int* __restrict__ dst, float* __restrict__ z, int E) {
  const int g = threadIdx.x >> 4;
  const int l = threadIdx.x & 15;
  const int e0 = blockIdx.x * 32 + g * 2;
  if (e0 >= E) return;
  const int e1 = e0 + 1;
  const bool has1 = e1 < E;

  const int u0 = src[e0], v0 = dst[e0];
  const int u1 = has1 ? src[e1] : u0;
  const int v1 = has1 ? dst[e1] : v0;

  const float4* Au0 = (const float4*)(A + (size_t)u0 * HID) + l * 2;
  const float4* Bv0 = (const float4*)(B + (size_t)v0 * HID) + l * 2;
  const float4* Au1 = (const float4*)(A + (size_t)u1 * HID) + l * 2;
  const float4* Bv1 = (const float4*)(B + (size_t)v1 * HID) + l * 2;

  const float4 a00 = Au0[0], a01 = Au0[1];
  const float4 b00 = Bv0[0], b01 = Bv0[1];
  const float4 a10 = Au1[0], a11 = Au1[1];
  const float4 b10 = Bv1[0], b11 = Bv1[1];

  const float4 c0 = *(const float4*)(b1 + l * 8);
  const float4 c1 = *(const float4*)(b1 + l * 8 + 4);
  const float4 w0 = *(const float4*)(W2 + l * 8);
  const float4 w1 = *(const float4*)(W2 + l * 8 + 4);
  const float bias2 = b2[0];

  float p0 = fmaxf(a00.x + b00.x + c0.x, 0.f) * w0.x
           + fmaxf(a00.y + b00.y + c0.y, 0.f) * w0.y
           + fmaxf(a00.z + b00.z + c0.z, 0.f) * w0.z
           + fmaxf(a00.w + b00.w + c0.w, 0.f) * w0.w
           + fmaxf(a01.x + b01.x + c1.x, 0.f) * w1.x
           + fmaxf(a01.y + b01.y + c1.y, 0.f) * w1.y
           + fmaxf(a01.z + b01.z + c1.z, 0.f) * w1.z
           + fmaxf(a01.w + b01.w + c1.w, 0.f) * w1.w;
  float p1 = fmaxf(a10.x + b10.x + c0.x, 0.f) * w0.x
           + fmaxf(a10.y + b10.y + c0.y, 0.f) * w0.y
           + fmaxf(a10.z + b10.z + c0.z, 0.f) * w0.z
           + fmaxf(a10.w + b10.w + c0.w, 0.f) * w0.w
           + fmaxf(a11.x + b11.x + c1.x, 0.f) * w1.x
           + fmaxf(a11.y + b11.y + c1.y, 0.f) * w1.y
           + fmaxf(a11.z + b11.z + c1.z, 0.f) * w1.z
           + fmaxf(a11.w + b11.w + c1.w, 0.f) * w1.w;

#pragma unroll
  for (int m = 8; m >= 1; m >>= 1) {
    p0 += __shfl_xor(p0, m);
    p1 += __shfl_xor(p1, m);
  }
  if (l == 0) {
    z[e0] = p0 + bias2;
    if (has1) z[e1] = p1 + bias2;
  }
}

// ---------------------------------------------------------------------------
// Kernel 4: per-node log-softmax + K Gumbel rounds. TWO nodes per wave
// (half-wave each; deg<=32 fast path covers all but ~5 Poisson(16) nodes).
// Works in ex = exp(s) space: argmax(ex) == argmax(s), fused max+argmax pair
// reduction, sum reduction independent of max. Fast __logf/__expf (native
// v_log/v_exp, rel err ~1e-7 — same order as libm-vs-numpy differences).
// Segment-constant factors cancel in both argmax and the softmax ratio.
// ---------------------------------------------------------------------------
__global__ __launch_bounds__(256) void seg_sample(
    const float* __restrict__ z, const float* __restrict__ U,
    const int* __restrict__ dst, const int* __restrict__ rs,
    float* __restrict__ out_sel, float* __restrict__ out_soft,
    int N, int E, int K) {
  const int t = threadIdx.x;
  const int lane = t & 63;
  const int half = lane >> 5;
  const int hl = lane & 31;
  const int n = blockIdx.x * 8 + (t >> 6) * 2 + half;
  const float INVTAU = 1.0f / 0.9991f;

  int start = 0, deg = 0;
  if (n < N) { start = rs[n]; deg = rs[n + 1] - start; }

  if (__all(deg <= 32)) {
    // ---- fast path: half-wave per node ----
    if (n >= N) return;
    if (deg == 0) {
      if (hl == 0)
        for (int k = 0; k < K; ++k) out_sel[(size_t)k * N + n] = -2147483648.0f;
      return;
    }
    const bool act = hl < deg;
    const int e = start + (act ? hl : 0);
    const float zv = act ? z[e] : -INFINITY;
    const int d = act ? dst[e] : -1;

    float zmax = zv;
#pragma unroll
    for (int m = 16; m >= 1; m >>= 1) zmax = fmaxf(zmax, __shfl_xor(zmax, m));
    float den = act ? __expf(zv - zmax) : 0.f;
#pragma unroll
    for (int m = 16; m >= 1; m >>= 1) den += __shfl_xor(den, m);
    const float lpb = (zv - zmax) - __logf(den);  // per-edge log-prob

    for (int k = 0; k < K; ++k) {
      float ex = 0.f;
      if (act) {
        const float uu = U[(size_t)k * E + e];
        const float t2 = -__logf(uu);
        const float g = -__logf(t2);
        ex = __expf((lpb + g) * INVTAU);  // exp(s); s in [-19, 15] -> safe
      }
      float d2 = ex;
      float mx = ex;
      int md = d;
#pragma unroll
      for (int m = 16; m >= 1; m >>= 1) {
        d2 += __shfl_xor(d2, m);
        const float ox = __shfl_xor(mx, m);
        const int od = __shfl_xor(md, m);
        if (ox > mx) { mx = ox; md = od; }
        else if (ox == mx) md = max(md, od);
      }
      if (hl == 0) out_sel[(size_t)k * N + n] = (float)md;
      if (act) {
        const float inv = __builtin_amdgcn_rcpf(d2);
        out_soft[(size_t)k * E + e] = ex * inv;
      }
    }
    return;
  }

  // ---- general path (some deg > 32, ~5 nodes): full wave per node, x2 ----
  const int wbase = blockIdx.x * 8 + (t >> 6) * 2;
  for (int j = 0; j < 2; ++j) {
    const int nn = wbase + j;
    if (nn >= N) continue;
    const int st = rs[nn];
    const int dg = rs[nn + 1] - st;
    if (dg == 0) {
      if (lane == 0)
        for (int k = 0; k < K; ++k) out_sel[(size_t)k * N + nn] = -2147483648.0f;
      continue;
    }
    float zmax = -INFINITY;
    for (int c = lane; c < dg; c += 64) zmax = fmaxf(zmax, z[st + c]);
#pragma unroll
    for (int m = 32; m >= 1; m >>= 1) zmax = fmaxf(zmax, __shfl_xor(zmax, m));
    float den = 0.f;
    for (int c = lane; c < dg; c += 64) den += expf(z[st + c] - zmax);
#pragma unroll
    for (int m = 32; m >= 1; m >>= 1) den += __shfl_xor(den, m);
    const float logd = logf(den);

    for (int k = 0; k < K; ++k) {
      float m2 = -INFINITY;
      for (int c = lane; c < dg; c += 64) {
        const int e = st + c;
        const float g = -logf(-logf(U[(size_t)k * E + e]));
        const float s = ((z[e] - zmax) - logd + g) * INVTAU;
        m2 = fmaxf(m2, s);
      }
#pragma unroll
      for (int m = 32; m >= 1; m >>= 1) m2 = fmaxf(m2, __shfl_xor(m2, m));
      float d2 = 0.f;
      int cand = -1;
      for (int c = lane; c < dg; c += 64) {
        const int e = st + c;
        const float g = -logf(-logf(U[(size_t)k * E + e]));
        const float s = ((z[e] - zmax) - logd + g) * INVTAU;
        d2 += expf(s - m2);
        if (s >= m2) cand = max(cand, dst[e]);
      }
#pragma unroll
      for (int m = 32; m >= 1; m >>= 1) d2 += __shfl_xor(d2, m);
#pragma unroll
      for (int m = 32; m >= 1; m >>= 1) cand = max(cand, __shfl_xor(cand, m));
      if (lane == 0) out_sel[(size_t)k * N + nn] = (float)cand;
      for (int c = lane; c < dg; c += 64) {
        const int e = st + c;
        const float g = -logf(-logf(U[(size_t)k * E + e]));
        const float s = ((z[e] - zmax) - logd + g) * INVTAU;
        out_soft[(size_t)k * E + e] = expf(s - m2) / d2;
      }
    }
  }
}

// ---------------------------------------------------------------------------
extern "C" void kernel_launch(void* const* d_in, const int* in_sizes, int n_in,
                              void* d_out, int out_size, void* d_ws, size_t ws_size,
                              hipStream_t stream) {
  const float* X  = (const float*)d_in[0];  // (N, 128)
  const float* W1 = (const float*)d_in[1];  // (256, 128)
  const float* b1 = (const float*)d_in[2];  // (128,)
  const float* W2 = (const float*)d_in[3];  // (128,)
  const float* b2 = (const float*)d_in[4];  // (1,)
  const float* U  = (const float*)d_in[5];  // (K, E)
  const int* src  = (const int*)d_in[6];    // (E,) sorted
  const int* dst  = (const int*)d_in[7];    // (E,)
  const int E = in_sizes[6];
  const int K = in_sizes[5] / E;
  const int N = in_sizes[0] / FEAT;

  // workspace: A (N*128 f32) | B (N*128 f32) | z (E f32) | rs (N+1 i32)
  float* A = (float*)d_ws;
  float* B = A + (size_t)N * HID;
  float* z = B + (size_t)N * HID;
  int* rs  = (int*)(z + E);

  float* out_sel  = (float*)d_out;                  // (K, N) as f32
  float* out_soft = (float*)d_out + (size_t)K * N;  // (K, E)

  hipLaunchKernelGGL(gemm_ab, dim3((N + 127) / 128, 4), dim3(256), 0, stream,
                     X, W1, A, B, N);
  hipLaunchKernelGGL(row_offsets, dim3((N + 256) / 256), dim3(256), 0, stream,
                     src, rs, N, E);
  hipLaunchKernelGGL(edge_z, dim3((E + 31) / 32), dim3(256), 0, stream,
                     A, B, b1, W2, b2, src, dst, z, E);
  hipLaunchKernelGGL(seg_sample, dim3((N + 7) / 8), dim3(256), 0, stream,
                     z, U, dst, rs, out_sel, out_soft, N, E, K);
}